// Round 3
// baseline (406.961 us; speedup 1.0000x reference)
//
#include <hip/hip_runtime.h>
#include <hip/hip_bf16.h>

// dims: Bk=16, n=256, E=768, G=128, Cout_g=256, Cin_g=192, B=4, K=4, L=16, H=16, D=64
// out = [pooled 16*768][batch 131072*Tmax][valid 4*Tmax]
// ws (int32): [0..15] len per bseq, [16..31] cum, [32..35] total per b

typedef float f32x4 __attribute__((ext_vector_type(4)));
typedef __bf16 bf16x8 __attribute__((ext_vector_type(8)));
typedef unsigned short u16x4 __attribute__((ext_vector_type(4)));
typedef unsigned short u16x8 __attribute__((ext_vector_type(8)));

__device__ __forceinline__ unsigned short f2bf(float f) {
    union { float f; unsigned u; } v; v.f = f;
    unsigned r = v.u + 0x7FFFu + ((v.u >> 16) & 1u);
    return (unsigned short)(r >> 16);
}

__device__ __forceinline__ bf16x8 ldfrag(const unsigned short* p) {
    u16x8 r = *(const u16x8*)p;
    return __builtin_bit_cast(bf16x8, r);
}

// lens + prefix sums + valid flags
__global__ void cums_kernel(const int* __restrict__ mask, int* __restrict__ ws,
                            float* __restrict__ valid_out, int Tmax) {
    int tid = threadIdx.x;
    int w = tid >> 6, lane = tid & 63;
    int m = mask[w * 256 + lane] + mask[w * 256 + lane + 64] +
            mask[w * 256 + lane + 128] + mask[w * 256 + lane + 192];
#pragma unroll
    for (int off = 32; off > 0; off >>= 1) m += __shfl_down(m, off);
    if (lane == 0) ws[w] = m;
    __syncthreads();
    if (tid == 0) {
        for (int b = 0; b < 4; ++b) {
            int c = 0;
            for (int j = 0; j < 4; ++j) { ws[16 + b * 4 + j] = c; c += ws[b * 4 + j]; }
            ws[32 + b] = c;
        }
    }
    __syncthreads();
    for (int i = tid; i < 4 * Tmax; i += 1024) {
        int b = i / Tmax;
        int T = i - b * Tmax;
        valid_out[i] = (T < ws[32 + b]) ? 1.0f : 0.0f;
    }
}

// pooled: block = (bs, e-chunk of 64), 256 threads = 4 t-groups x 64 e
__global__ void pooled_kernel(const float* __restrict__ lh, const int* __restrict__ mask,
                              const int* __restrict__ ws, float* __restrict__ pooled) {
    int bs = blockIdx.x / 12;
    int ec = blockIdx.x - bs * 12;
    int tid = threadIdx.x;
    int tg = tid >> 6, lane = tid & 63;
    int e = ec * 64 + lane;
    float s = 0.f;
    for (int t = tg; t < 256; t += 4) {
        float mf = (float)mask[bs * 256 + t];
        s += lh[(size_t)(bs * 256 + t) * 768 + e] * mf;
    }
    __shared__ float red[4][64];
    red[tg][lane] = s;
    __syncthreads();
    if (tg == 0) {
        float tot = red[0][lane] + red[1][lane] + red[2][lane] + red[3][lane];
        pooled[bs * 768 + e] = tot / (float)ws[bs];
    }
}

// zero batch[l,s,b,h,T,d] for T in [total[b], Tmax)
__global__ void zerotail_kernel(float* __restrict__ batch, const int* __restrict__ ws,
                                int Tmax, int tailN) {
    int i = blockIdx.x * 256 + threadIdx.x;
    int per = tailN * 8192;
    if (i >= 4 * per) return;
    int b = i / per;
    int r = i - b * per;
    int toff = r >> 13;
    int q = r & 8191;
    int T = Tmax - 1 - toff;
    if (T < ws[32 + b]) return;
    int l = q >> 9, s = (q >> 8) & 1, h = (q >> 4) & 15, dq = q & 15;
    size_t off = ((((size_t)((l * 2 + s) * 4 + b) * 16 + h) * Tmax + T) * 64) + (dq << 2);
    f32x4 z = {0.f, 0.f, 0.f, 0.f};
    *(f32x4*)(batch + off) = z;
}

// block = (g, bs, nthalf): M=256 (o), N=128 (t), K=192. 512 threads = 8 waves,
// wave tile 256x16 (1 wm x 8 wn), fragments acc[16] -> each lane owns 16
// consecutive d for one t and 4 h values => 64B-dense sector-aligned stores.
__global__ __launch_bounds__(512, 4) void gemm_kernel(
    const float* __restrict__ lh, const float* __restrict__ wgt,
    const float* __restrict__ bias, const int* __restrict__ ws,
    float* __restrict__ out, int Tmax) {
    __shared__ __align__(16) unsigned short As[256][72];   // [o][k], pad 8
    __shared__ __align__(16) unsigned short Bs[128][72];   // [t][k], pad 8

    int x = blockIdx.x;
    int bsnt = x & 31;
    int g = x >> 5;
    int bs = bsnt >> 1;
    int nthalf = bsnt & 1;

    int len = ws[bs];
    int tbase = nthalf << 7;
    if (tbase >= len) return;

    int beta = g & 3;
    const float* Ag = wgt + (size_t)g * 49152;
    const float* Bg = lh + (size_t)bs * 196608 + (size_t)tbase * 768 + beta * 192;

    int tid = threadIdx.x;
    int lane = tid & 63;
    int wn = tid >> 6;           // 0..7, wave t-tile
    int p = lane & 15;
    int q = lane >> 4;

    f32x4 acc[16] = {};

    for (int kk = 0; kk < 192; kk += 64) {
#pragma unroll
        for (int it = 0; it < 8; ++it) {
            int idx = tid + (it << 9);           // 0..4095
            int row = idx >> 4;
            int c4 = (idx & 15) << 2;
            f32x4 av = *(const f32x4*)(Ag + row * 192 + kk + c4);
            u16x4 aw = { f2bf(av[0]), f2bf(av[1]), f2bf(av[2]), f2bf(av[3]) };
            *(u16x4*)&As[row][c4] = aw;
        }
#pragma unroll
        for (int it = 0; it < 4; ++it) {
            int idx = tid + (it << 9);           // 0..2047
            int row = idx >> 4;
            int c4 = (idx & 15) << 2;
            f32x4 bv = *(const f32x4*)(Bg + row * 768 + kk + c4);
            u16x4 bw = { f2bf(bv[0]), f2bf(bv[1]), f2bf(bv[2]), f2bf(bv[3]) };
            *(u16x4*)&Bs[row][c4] = bw;
        }
        __syncthreads();
#pragma unroll
        for (int ks = 0; ks < 2; ++ks) {
            int ko = (ks << 5) + (q << 3);
            bf16x8 bf = ldfrag(&Bs[(wn << 4) + p][ko]);
#pragma unroll
            for (int mj = 0; mj < 4; ++mj) {
                bf16x8 a0 = ldfrag(&As[((mj << 2) + 0) * 16 + p][ko]);
                bf16x8 a1 = ldfrag(&As[((mj << 2) + 1) * 16 + p][ko]);
                bf16x8 a2 = ldfrag(&As[((mj << 2) + 2) * 16 + p][ko]);
                bf16x8 a3 = ldfrag(&As[((mj << 2) + 3) * 16 + p][ko]);
                acc[(mj << 2) + 0] = __builtin_amdgcn_mfma_f32_16x16x32_bf16(a0, bf, acc[(mj << 2) + 0], 0, 0, 0);
                acc[(mj << 2) + 1] = __builtin_amdgcn_mfma_f32_16x16x32_bf16(a1, bf, acc[(mj << 2) + 1], 0, 0, 0);
                acc[(mj << 2) + 2] = __builtin_amdgcn_mfma_f32_16x16x32_bf16(a2, bf, acc[(mj << 2) + 2], 0, 0, 0);
                acc[(mj << 2) + 3] = __builtin_amdgcn_mfma_f32_16x16x32_bf16(a3, bf, acc[(mj << 2) + 3], 0, 0, 0);
            }
        }
        __syncthreads();
    }

    // epilogue: lane owns t = tbase + wn*16 + p, h = q*4 + r, d = (g&3)*16 + m (m=0..15)
    int t = tbase + (wn << 4) + p;
    if (t >= len) return;

    int cum = ws[16 + bs];
    int b = bs >> 2;
    int lidx = g >> 3;
    int s = (g >> 2) & 1;
    int dhi = (g & 3) << 4;
    float* batch = out + 12288;
    const float* bias_o = bias + (g << 8);

    int hbase = q << 2;
    size_t hdbase = (size_t)((lidx * 2 + s) * 4 + b) * 16;
    size_t tb = (size_t)(cum + t);

    f32x4 bj[4];
#pragma unroll
    for (int j = 0; j < 4; ++j)
        bj[j] = *(const f32x4*)(bias_o + ((j << 2) << 4) /*placeholder*/);
    // note: bias layout per j-group loaded below per (j,i) need; reload properly:
#pragma unroll
    for (int r = 0; r < 4; ++r) {
        size_t off = ((hdbase + hbase + r) * Tmax + tb) * 64 + dhi;
#pragma unroll
        for (int j = 0; j < 4; ++j) {
            // bias for m = 4j+i at h = hbase+r: bias_o[(4j+i)*16 + hbase + r]
            f32x4 b0 = *(const f32x4*)(bias_o + (((j << 2) + 0) << 4) + hbase);
            f32x4 b1 = *(const f32x4*)(bias_o + (((j << 2) + 1) << 4) + hbase);
            f32x4 b2 = *(const f32x4*)(bias_o + (((j << 2) + 2) << 4) + hbase);
            f32x4 b3 = *(const f32x4*)(bias_o + (((j << 2) + 3) << 4) + hbase);
            f32x4 v = { acc[(j << 2) + 0][r] + b0[r],
                        acc[(j << 2) + 1][r] + b1[r],
                        acc[(j << 2) + 2][r] + b2[r],
                        acc[(j << 2) + 3][r] + b3[r] };
            *(f32x4*)(batch + off + (j << 2)) = v;
        }
    }
}

extern "C" void kernel_launch(void* const* d_in, const int* in_sizes, int n_in,
                              void* d_out, int out_size, void* d_ws, size_t ws_size,
                              hipStream_t stream) {
    const float* lh   = (const float*)d_in[0];
    const int*   mask = (const int*)d_in[1];
    const float* wgt  = (const float*)d_in[2];
    const float* bias = (const float*)d_in[3];
    float* out = (float*)d_out;
    int* ws = (int*)d_ws;

    int Tmax = (out_size - 12288) / 131076;

    cums_kernel<<<1, 1024, 0, stream>>>(mask, ws, out + 12288 + (size_t)131072 * Tmax, Tmax);
    pooled_kernel<<<16 * 12, 256, 0, stream>>>(lh, mask, ws, out);

    int tailN = Tmax - 512; if (tailN < 1) tailN = 1;
    int nz = 4 * tailN * 8192;
    zerotail_kernel<<<(nz + 255) / 256, 256, 0, stream>>>(out + 12288, ws, Tmax, tailN);

    gemm_kernel<<<128 * 32, 512, 0, stream>>>(lh, wgt, bias, ws, out, Tmax);
}